// Round 1
// baseline (144.048 us; speedup 1.0000x reference)
//
#include <hip/hip_runtime.h>

// Problem constants (B=2, S=2048, H=8, E=64).
// Harness passes f16 tensors upcast to FLOAT32 (in and out). Internally f16
// compute (lossless re-narrowing of f16-origin data), fp32 MFMA accumulation.
#define S_LEN 2048
#define NH    8
#define EMB   64
#define BM    64    // q rows per block (16 per wave)
#define BN    64    // kv tile length (64 -> 25KB LDS -> 6 blocks/CU)
#define NKT   (S_LEN / BN)          // 32 kv tiles
#define NSPLIT 3    // KV splits: 16 bh x 32 qt x 3 = 1536 blocks = 6/CU exactly
#define PSTR  72    // padded LDS row stride for P (f16 elems, 144B: 16B-aligned)
#define M_INIT  (-1.0e4f)
#define EXP_CLAMP (-80.0f)

typedef _Float16 half8   __attribute__((ext_vector_type(8)));
typedef _Float16 half4   __attribute__((ext_vector_type(4)));
typedef float    float4_t __attribute__((ext_vector_type(4)));
typedef float    float8_t __attribute__((ext_vector_type(8)));

__device__ inline half8 cvt8(const float* p) {
    float8_t f = *reinterpret_cast<const float8_t*>(p);
    half8 h;
    #pragma unroll
    for (int j = 0; j < 8; ++j) h[j] = (_Float16)f[j];
    return h;
}

// async global->LDS, 16B per lane; LDS dest = uniform base + lane*16
__device__ inline void gload_lds16(const _Float16* g, _Float16* l) {
    __builtin_amdgcn_global_load_lds(
        (const __attribute__((address_space(1))) void*)g,
        (__attribute__((address_space(3))) void*)l, 16, 0, 0);
}

// ---------------------------------------------------------------------------
// Launch 1: Q projection -> d_out f32 [B,H,S,E], pre-scaled by 0.125.
// ---------------------------------------------------------------------------
__global__ __launch_bounds__(256) void proj_q(
    const float* __restrict__ X, const float* __restrict__ W,
    const float* __restrict__ bias, float* __restrict__ Out)
{
    const int tid  = threadIdx.x;
    const int lane = tid & 63;
    const int wave = tid >> 6;
    const int l15  = lane & 15;
    const int quad = lane >> 4;
    const int gwave = blockIdx.x * 4 + wave;

    half8 wf[4][2];
    #pragma unroll
    for (int ft = 0; ft < 4; ++ft)
        #pragma unroll
        for (int ks = 0; ks < 2; ++ks)
            wf[ft][ks] = cvt8(W + (ft * 16 + l15) * 64 + ks * 32 + quad * 8);
    float bv[4];
    #pragma unroll
    for (int ft = 0; ft < 4; ++ft) bv[ft] = bias[ft * 16 + l15];

    #pragma unroll
    for (int rt2 = 0; rt2 < 2; ++rt2) {
        const int rt = gwave * 2 + rt2;
        const int arow = rt * 16 + l15;
        half8 xf[2];
        #pragma unroll
        for (int ks = 0; ks < 2; ++ks)
            xf[ks] = cvt8(X + (long)arow * 64 + ks * 32 + quad * 8);
        float4_t acc[4];
        #pragma unroll
        for (int ft = 0; ft < 4; ++ft) {
            acc[ft] = (float4_t){0.f, 0.f, 0.f, 0.f};
            #pragma unroll
            for (int ks = 0; ks < 2; ++ks)
                acc[ft] = __builtin_amdgcn_mfma_f32_16x16x32_f16(
                    xf[ks], wf[ft][ks], acc[ft], 0, 0, 0);
        }
        #pragma unroll
        for (int r = 0; r < 4; ++r) {
            const int row = rt * 16 + quad * 4 + r;     // (b*S+s)*H+h
            const int b = row >> 14;
            const int s = (row >> 3) & 2047;
            const int h = row & 7;
            const long orow = ((long)(b * NH + h) * S_LEN + s) * EMB;
            #pragma unroll
            for (int ft = 0; ft < 4; ++ft) {
                const _Float16 v =
                    (_Float16)(acc[ft][r] + bv[ft]) * (_Float16)0.125f;
                Out[orow + ft * 16 + l15] = (float)v;
            }
        }
    }
}

// ---------------------------------------------------------------------------
// Launch 2: K and V projections fused, writing attention-ready layouts:
//   seg 0: K -> KT8[bh][f/8][s][f%8]
//   seg 1: V -> VT8[bh][s/8][f][s%8]
// ---------------------------------------------------------------------------
__global__ __launch_bounds__(256) void proj_kv(
    const float* __restrict__ k_in, const float* __restrict__ v_in,
    const float* __restrict__ Wk, const float* __restrict__ bk,
    const float* __restrict__ Wv, const float* __restrict__ bv_,
    _Float16* __restrict__ KT8, _Float16* __restrict__ VT8)
{
    const int seg = blockIdx.x >> 8;          // 0=K, 1=V
    const int bid = blockIdx.x & 255;
    const float* X    = seg ? v_in : k_in;
    const float* W    = seg ? Wv : Wk;
    const float* bias = seg ? bv_ : bk;

    const int tid  = threadIdx.x;
    const int lane = tid & 63;
    const int wave = tid >> 6;
    const int l15  = lane & 15;
    const int quad = lane >> 4;
    const int gwave = bid * 4 + wave;

    half8 wf[4][2];
    #pragma unroll
    for (int ft = 0; ft < 4; ++ft)
        #pragma unroll
        for (int ks = 0; ks < 2; ++ks)
            wf[ft][ks] = cvt8(W + (ft * 16 + l15) * 64 + ks * 32 + quad * 8);
    float bv[4];
    #pragma unroll
    for (int ft = 0; ft < 4; ++ft) bv[ft] = bias[ft * 16 + l15];

    #pragma unroll
    for (int rt2 = 0; rt2 < 2; ++rt2) {
        const int rt = gwave * 2 + rt2;
        const int arow = rt * 16 + l15;
        half8 xf[2];
        #pragma unroll
        for (int ks = 0; ks < 2; ++ks)
            xf[ks] = cvt8(X + (long)arow * 64 + ks * 32 + quad * 8);
        float4_t acc[4];
        #pragma unroll
        for (int ft = 0; ft < 4; ++ft) {
            acc[ft] = (float4_t){0.f, 0.f, 0.f, 0.f};
            #pragma unroll
            for (int ks = 0; ks < 2; ++ks)
                acc[ft] = __builtin_amdgcn_mfma_f32_16x16x32_f16(
                    xf[ks], wf[ft][ks], acc[ft], 0, 0, 0);
        }
        #pragma unroll
        for (int r = 0; r < 4; ++r) {
            const int row = rt * 16 + quad * 4 + r;     // (b*S+s)*H+h
            const int b = row >> 14;
            const int s = (row >> 3) & 2047;
            const int h = row & 7;
            const int bh = b * NH + h;
            #pragma unroll
            for (int ft = 0; ft < 4; ++ft) {
                const _Float16 v = (_Float16)(acc[ft][r] + bv[ft]);
                const int f = ft * 16 + l15;
                if (seg == 0)
                    KT8[(((long)bh * 8 + (f >> 3)) * S_LEN + s) * 8 + (f & 7)] = v;
                else
                    VT8[(((long)bh * 256 + (s >> 3)) * 64 + f) * 8 + (s & 7)] = v;
            }
        }
    }
}

// ---------------------------------------------------------------------------
// Launch 3: flash attention partials, KV-split=3, S^T orientation, BN=64.
// LDS 25 KB/block -> 6 blocks/CU resident (grid = exactly 6x256). K/V tiles
// staged via global_load_lds and shared block-wide; S^T = K*Q^T so each lane
// owns one q-row -> scalar m/l, 2-shuffle reductions, b64 P stores.
//
// XCD-aware swizzle (T1): all 1536 blocks are co-resident; the old bh=bx/96
// mapping spread every head across all 8 XCDs, so each 4 MiB L2 serviced all
// 16 heads' K/V (8 MB) + Q (16 MB f32) -> thrash, and the ~262 MB of staged
// K/V re-reads went to HBM. blockIdx maps to XCD round-robin (bx & 7, m09),
// so decompose bx = j*8 + xcd and give each XCD exactly 2 heads:
// hot set/XCD = 2*(K+V 0.5MB + Q 0.5MB) = 2 MB < 4 MB L2 -> staging L2-hits.
// ---------------------------------------------------------------------------
__global__ __launch_bounds__(256, 6) void attn_part(
    const _Float16* __restrict__ KT, const _Float16* __restrict__ VT,
    const float* __restrict__ Qbuf,
    _Float16* __restrict__ p0, _Float16* __restrict__ p1,
    _Float16* __restrict__ p2, float* __restrict__ stats)
{
    __shared__ __align__(16) _Float16 Kb[8 * 64 * 8];    // 8 KB [ec][tl][ej]
    __shared__ __align__(16) _Float16 Vb[8 * 64 * 8];    // 8 KB [tc][e][tj]
    __shared__ __align__(16) _Float16 Pl[4][16 * PSTR];  // 9 KB per-wave P: [q][t]

    const int tid  = threadIdx.x;
    const int lane = tid & 63;
    const int wave = tid >> 6;
    const int l15  = lane & 15;
    const int quad = lane >> 4;

    // --- XCD-aware decomposition: 1536 = 8 XCD * (2 heads * 96 blocks) ---
    const int bx   = blockIdx.x;
    const int xcd  = bx & 7;                 // hardware XCD (round-robin)
    const int j    = bx >> 3;                // 0..191 within this XCD
    const int hh   = (j >= 96) ? 1 : 0;      // which of the 2 heads here
    const int within = j - hh * 96;          // 0..95 = qt*NSPLIT + sp
    const int bh   = xcd * 2 + hh;
    const int qt   = within / NSPLIT;
    const int sp   = within - qt * NSPLIT;

    const long base = (long)bh * S_LEN * EMB;
    const int qrow0 = qt * BM + wave * 16;

    const _Float16* kg = KT + (long)bh * 8 * S_LEN * 8;  // head base in KT8

    half8 qf[2];   // B-frag: Q[n = q-row l15][e = ks*32+quad*8+j]
    #pragma unroll
    for (int ks = 0; ks < 2; ++ks)
        qf[ks] = cvt8(Qbuf + base + (long)(qrow0 + l15) * EMB + ks * 32 + quad * 8);

    float4_t o[4];
    #pragma unroll
    for (int et = 0; et < 4; ++et) o[et] = (float4_t){0.f, 0.f, 0.f, 0.f};
    float m_run = M_INIT, l_run = 0.f;    // this lane's q-row = l15

    const int kb = (sp * NKT) / NSPLIT, ke = ((sp + 1) * NKT) / NSPLIT; // 10/11/11
    for (int kt = kb; kt < ke; ++kt) {
        if (kt > kb) __syncthreads();     // prev-iter consumers done
        const int t0 = kt * BN;
        #pragma unroll
        for (int rr = 0; rr < 2; ++rr) {  // K tile: 512 units [ec][tl][ej]
            const int u = rr * 256 + tid;
            const int ec = u >> 6, tl = u & 63;
            gload_lds16(kg + ((long)ec * S_LEN + t0 + tl) * 8, Kb + u * 8);
        }
        const _Float16* vg = VT + ((long)bh * 256 + (t0 >> 3)) * 512;
        #pragma unroll
        for (int rr = 0; rr < 2; ++rr) {  // V tile: contiguous 8 KB
            const int u = rr * 256 + tid;
            gload_lds16(vg + u * 8, Vb + u * 8);
        }
        __syncthreads();                  // drains vmcnt -> tiles visible

        // S^T = K Q^T : 4 n-tiles of 16 t-rows
        float4_t sacc[4];
        #pragma unroll
        for (int nt = 0; nt < 4; ++nt) sacc[nt] = (float4_t){0.f, 0.f, 0.f, 0.f};
        #pragma unroll
        for (int nt = 0; nt < 4; ++nt)
            #pragma unroll
            for (int ks = 0; ks < 2; ++ks) {
                half8 kf = *reinterpret_cast<const half8*>(   // A: K[m=t][e]
                    Kb + (ks * 4 + quad) * 512 + (nt * 16 + l15) * 8);
                sacc[nt] = __builtin_amdgcn_mfma_f32_16x16x32_f16(
                    kf, qf[ks], sacc[nt], 0, 0, 0);
            }

        // softmax for q-row l15: 16 local values (t = nt*16 + quad*4 + r)
        float mx = sacc[0][0];
        #pragma unroll
        for (int nt = 0; nt < 4; ++nt)
            #pragma unroll
            for (int r = 0; r < 4; ++r) mx = fmaxf(mx, sacc[nt][r]);
        mx = fmaxf(mx, __shfl_xor(mx, 16));
        mx = fmaxf(mx, __shfl_xor(mx, 32));

        const float mn = fmaxf(m_run, mx);
        const float alpha = __expf(fmaxf(m_run - mn, EXP_CLAMP));
        m_run = mn;

        _Float16* Pw = Pl[wave];
        float rsum = 0.f;
        #pragma unroll
        for (int nt = 0; nt < 4; ++nt) {
            half4 ph;
            #pragma unroll
            for (int r = 0; r < 4; ++r) {
                const float p = __expf(sacc[nt][r] - m_run);
                rsum += p;
                ph[r] = (_Float16)p;
            }
            // P[q=l15][t = nt*16 + quad*4 + 0..3] : one b64 write
            *reinterpret_cast<half4*>(&Pw[l15 * PSTR + nt * 16 + quad * 4]) = ph;
        }
        rsum += __shfl_xor(rsum, 16);
        rsum += __shfl_xor(rsum, 32);
        l_run = l_run * alpha + rsum;

        // rescale O (rows quad*4+r need alpha of lane quad*4+r)
        #pragma unroll
        for (int r = 0; r < 4; ++r) {
            const float ar = __shfl(alpha, quad * 4 + r);
            #pragma unroll
            for (int et = 0; et < 4; ++et) o[et][r] *= ar;
        }
        // no barrier: P write->read is intra-wave (compiler lgkmcnt)

        // O += P V : A-frag = P[m=l15][t=ts*32+quad*8+j], B-frag from Vb LDS
        #pragma unroll
        for (int ts = 0; ts < 2; ++ts) {
            half8 pf = *reinterpret_cast<const half8*>(
                &Pw[l15 * PSTR + ts * 32 + quad * 8]);
            #pragma unroll
            for (int et = 0; et < 4; ++et) {
                half8 vf = *reinterpret_cast<const half8*>(
                    Vb + (ts * 4 + quad) * 512 + (et * 16 + l15) * 8);
                o[et] = __builtin_amdgcn_mfma_f32_16x16x32_f16(pf, vf, o[et], 0, 0, 0);
            }
        }
    }

    // epilogue: normalized partial O-hat (f16) + (m,l) stats.
    _Float16* pp = (sp == 0) ? p0 : (sp == 1) ? p1 : p2;
    #pragma unroll
    for (int r = 0; r < 4; ++r) {
        const float lr = __shfl(l_run, quad * 4 + r);    // row quad*4+r's sum
        const float inv = 1.f / lr;
        const int row = qrow0 + quad * 4 + r;            // 0..2047 within head
        const int R = bh * S_LEN + row;                  // 0..32767 global row
        #pragma unroll
        for (int et = 0; et < 4; ++et)
            pp[(long)R * EMB + et * 16 + l15] = (_Float16)(o[et][r] * inv);
    }
    if (lane < 16) {                                     // lane i owns q-row i
        const int R = bh * S_LEN + qrow0 + lane;
        stats[sp * 32768 + R] = m_run;
        stats[(NSPLIT + sp) * 32768 + R] = l_run;
    }
}

// ---------------------------------------------------------------------------
// Launch 4: combine the 3 partials. O = sum w_i*Ohat_i, f16-round, f32 store.
// ---------------------------------------------------------------------------
__global__ __launch_bounds__(256) void attn_combine(
    const _Float16* __restrict__ p0, const _Float16* __restrict__ p1,
    const _Float16* __restrict__ p2, const float* __restrict__ stats,
    float* __restrict__ out)
{
    const int gid = blockIdx.x * 256 + threadIdx.x;      // 131072 threads
    const int R  = gid >> 2;
    const int c0 = (gid & 3) * 16;
    const float m0 = stats[R], m1 = stats[32768 + R], m2 = stats[2 * 32768 + R];
    const float l0 = stats[3 * 32768 + R], l1 = stats[4 * 32768 + R],
                l2 = stats[5 * 32768 + R];
    const float M = fmaxf(fmaxf(m0, m1), m2);
    float w0 = l0 * __expf(fmaxf(m0 - M, EXP_CLAMP));
    float w1 = l1 * __expf(fmaxf(m1 - M, EXP_CLAMP));
    float w2 = l2 * __expf(fmaxf(m2 - M, EXP_CLAMP));
    const float rinv = 1.f / (w0 + w1 + w2);
    w0 *= rinv; w1 *= rinv; w2 *= rinv;
    const long i0 = (long)R * EMB + c0;
    #pragma unroll
    for (int h = 0; h < 2; ++h) {
        half8 a = *reinterpret_cast<const half8*>(p0 + i0 + h * 8);
        half8 b = *reinterpret_cast<const half8*>(p1 + i0 + h * 8);
        half8 c = *reinterpret_cast<const half8*>(p2 + i0 + h * 8);
        #pragma unroll
        for (int j = 0; j < 8; ++j)
            out[i0 + h * 8 + j] = (float)(_Float16)(
                w0 * (float)a[j] + w1 * (float)b[j] + w2 * (float)c[j]);
    }
}

// ---------------------------------------------------------------------------
// 4 launches. Buffer plan (no d_ws; stream-ordered liveness):
//   L1 proj_q:  d_in[0](f32) -> d_out (f32, f16-rounded, pre-scaled)
//   L2 proj_kv: d_in[1] -> KT8 = d_in[0][0,4MB); d_in[2] -> VT8 = d_in[0][4,8MB)
//   L3 attn_part: reads KT8/VT8/d_out; p0,p1 -> d_in[2][0,8MB) (v_in dead),
//               p2 -> d_in[1][0,4MB) (k_in dead), stats -> d_in[1][4,4.75MB)
//   L4 combine -> d_out (Q dead)
// ---------------------------------------------------------------------------
extern "C" void kernel_launch(void* const* d_in, const int* in_sizes, int n_in,
                              void* d_out, int out_size, void* d_ws, size_t ws_size,
                              hipStream_t stream) {
    const float* q_in = (const float*)d_in[0];
    const float* k_in = (const float*)d_in[1];
    const float* v_in = (const float*)d_in[2];
    const float* Wq   = (const float*)d_in[3];
    const float* bq   = (const float*)d_in[4];
    const float* Wk   = (const float*)d_in[5];
    const float* bk   = (const float*)d_in[6];
    const float* Wv   = (const float*)d_in[7];
    const float* bv   = (const float*)d_in[8];
    float* out = (float*)d_out;

    _Float16* KT8   = (_Float16*)d_in[0];
    _Float16* VT8   = (_Float16*)((char*)d_in[0] + (4u << 20));
    _Float16* part0 = (_Float16*)d_in[2];
    _Float16* part1 = part0 + (long)2 * 1024 * 1024;           // +4 MB
    _Float16* part2 = (_Float16*)d_in[1];
    float*    stats = (float*)((char*)d_in[1] + (4u << 20));

    proj_q<<<256, 256, 0, stream>>>(q_in, Wq, bq, out);
    proj_kv<<<512, 256, 0, stream>>>(k_in, v_in, Wk, bk, Wv, bv, KT8, VT8);
    attn_part<<<16 * 32 * NSPLIT, 256, 0, stream>>>(KT8, VT8, out,
                                                    part0, part1, part2, stats);
    attn_combine<<<512, 256, 0, stream>>>(part0, part1, part2, stats, out);
}

// Round 2
// 142.517 us; speedup vs baseline: 1.0107x; 1.0107x over previous
//
#include <hip/hip_runtime.h>

// Problem constants (B=2, S=2048, H=8, E=64).
// Harness passes f16 tensors upcast to FLOAT32 (in and out). Internally f16
// compute (lossless re-narrowing of f16-origin data), fp32 MFMA accumulation.
#define S_LEN 2048
#define NH    8
#define EMB   64
#define BM    64    // q rows per block (16 per wave)
#define BN    64    // kv tile length
#define NKT   (S_LEN / BN)          // 32 kv tiles
#define NSPLIT 2    // KV splits: 16 bh x 32 qt x 2 = 1024 blocks = 4/CU exactly
#define M_INIT  (-1.0e4f)
#define EXP_CLAMP (-80.0f)
#define DEFER_THR 8.0f   // T13: skip rescale while max growth <= 8 (P <= e^8, f16-safe)

typedef _Float16 half8   __attribute__((ext_vector_type(8)));
typedef _Float16 half4   __attribute__((ext_vector_type(4)));
typedef float    float4_t __attribute__((ext_vector_type(4)));
typedef float    float8_t __attribute__((ext_vector_type(8)));

__device__ inline half8 cvt8(const float* p) {
    float8_t f = *reinterpret_cast<const float8_t*>(p);
    half8 h;
    #pragma unroll
    for (int j = 0; j < 8; ++j) h[j] = (_Float16)f[j];
    return h;
}

// async global->LDS, 16B per lane; LDS dest = uniform base + lane*16
__device__ inline void gload_lds16(const _Float16* g, _Float16* l) {
    __builtin_amdgcn_global_load_lds(
        (const __attribute__((address_space(1))) void*)g,
        (__attribute__((address_space(3))) void*)l, 16, 0, 0);
}

// ---------------------------------------------------------------------------
// Launch 1: Q projection -> d_out f32 [B,H,S,E], pre-scaled by 0.125.
// ---------------------------------------------------------------------------
__global__ __launch_bounds__(256) void proj_q(
    const float* __restrict__ X, const float* __restrict__ W,
    const float* __restrict__ bias, float* __restrict__ Out)
{
    const int tid  = threadIdx.x;
    const int lane = tid & 63;
    const int wave = tid >> 6;
    const int l15  = lane & 15;
    const int quad = lane >> 4;
    const int gwave = blockIdx.x * 4 + wave;

    half8 wf[4][2];
    #pragma unroll
    for (int ft = 0; ft < 4; ++ft)
        #pragma unroll
        for (int ks = 0; ks < 2; ++ks)
            wf[ft][ks] = cvt8(W + (ft * 16 + l15) * 64 + ks * 32 + quad * 8);
    float bv[4];
    #pragma unroll
    for (int ft = 0; ft < 4; ++ft) bv[ft] = bias[ft * 16 + l15];

    #pragma unroll
    for (int rt2 = 0; rt2 < 2; ++rt2) {
        const int rt = gwave * 2 + rt2;
        const int arow = rt * 16 + l15;
        half8 xf[2];
        #pragma unroll
        for (int ks = 0; ks < 2; ++ks)
            xf[ks] = cvt8(X + (long)arow * 64 + ks * 32 + quad * 8);
        float4_t acc[4];
        #pragma unroll
        for (int ft = 0; ft < 4; ++ft) {
            acc[ft] = (float4_t){0.f, 0.f, 0.f, 0.f};
            #pragma unroll
            for (int ks = 0; ks < 2; ++ks)
                acc[ft] = __builtin_amdgcn_mfma_f32_16x16x32_f16(
                    xf[ks], wf[ft][ks], acc[ft], 0, 0, 0);
        }
        #pragma unroll
        for (int r = 0; r < 4; ++r) {
            const int row = rt * 16 + quad * 4 + r;     // (b*S+s)*H+h
            const int b = row >> 14;
            const int s = (row >> 3) & 2047;
            const int h = row & 7;
            const long orow = ((long)(b * NH + h) * S_LEN + s) * EMB;
            #pragma unroll
            for (int ft = 0; ft < 4; ++ft) {
                const _Float16 v =
                    (_Float16)(acc[ft][r] + bv[ft]) * (_Float16)0.125f;
                Out[orow + ft * 16 + l15] = (float)v;
            }
        }
    }
}

// ---------------------------------------------------------------------------
// Launch 2: K and V projections fused, writing attention-ready layouts:
//   seg 0: K -> KT8[bh][f/8][s][f%8]
//   seg 1: V -> VT8[bh][s/8][f][s%8]
// ---------------------------------------------------------------------------
__global__ __launch_bounds__(256) void proj_kv(
    const float* __restrict__ k_in, const float* __restrict__ v_in,
    const float* __restrict__ Wk, const float* __restrict__ bk,
    const float* __restrict__ Wv, const float* __restrict__ bv_,
    _Float16* __restrict__ KT8, _Float16* __restrict__ VT8)
{
    const int seg = blockIdx.x >> 8;          // 0=K, 1=V
    const int bid = blockIdx.x & 255;
    const float* X    = seg ? v_in : k_in;
    const float* W    = seg ? Wv : Wk;
    const float* bias = seg ? bv_ : bk;

    const int tid  = threadIdx.x;
    const int lane = tid & 63;
    const int wave = tid >> 6;
    const int l15  = lane & 15;
    const int quad = lane >> 4;
    const int gwave = bid * 4 + wave;

    half8 wf[4][2];
    #pragma unroll
    for (int ft = 0; ft < 4; ++ft)
        #pragma unroll
        for (int ks = 0; ks < 2; ++ks)
            wf[ft][ks] = cvt8(W + (ft * 16 + l15) * 64 + ks * 32 + quad * 8);
    float bv[4];
    #pragma unroll
    for (int ft = 0; ft < 4; ++ft) bv[ft] = bias[ft * 16 + l15];

    #pragma unroll
    for (int rt2 = 0; rt2 < 2; ++rt2) {
        const int rt = gwave * 2 + rt2;
        const int arow = rt * 16 + l15;
        half8 xf[2];
        #pragma unroll
        for (int ks = 0; ks < 2; ++ks)
            xf[ks] = cvt8(X + (long)arow * 64 + ks * 32 + quad * 8);
        float4_t acc[4];
        #pragma unroll
        for (int ft = 0; ft < 4; ++ft) {
            acc[ft] = (float4_t){0.f, 0.f, 0.f, 0.f};
            #pragma unroll
            for (int ks = 0; ks < 2; ++ks)
                acc[ft] = __builtin_amdgcn_mfma_f32_16x16x32_f16(
                    xf[ks], wf[ft][ks], acc[ft], 0, 0, 0);
        }
        #pragma unroll
        for (int r = 0; r < 4; ++r) {
            const int row = rt * 16 + quad * 4 + r;     // (b*S+s)*H+h
            const int b = row >> 14;
            const int s = (row >> 3) & 2047;
            const int h = row & 7;
            const int bh = b * NH + h;
            #pragma unroll
            for (int ft = 0; ft < 4; ++ft) {
                const _Float16 v = (_Float16)(acc[ft][r] + bv[ft]);
                const int f = ft * 16 + l15;
                if (seg == 0)
                    KT8[(((long)bh * 8 + (f >> 3)) * S_LEN + s) * 8 + (f & 7)] = v;
                else
                    VT8[(((long)bh * 256 + (s >> 3)) * 64 + f) * 8 + (s & 7)] = v;
            }
        }
    }
}

// ---------------------------------------------------------------------------
// Launch 3: flash attention partials. KV-split=2, S^T orientation, BN=64.
// Round-2 restructure (counters: MfmaUtil 15 / VALUBusy 40 / Occ 41 / HBM 6%
// -> latency-bound on the staging drain, not BW/compute):
//  * Double-buffered K/V staging: issue next tile's global_load_lds at loop
//    top, compute current tile, then ONE __syncthreads (compiler drains
//    vmcnt there) -> staging latency hidden under a full compute phase.
//  * LDS = 16K K-dbuf + 16K V-dbuf + 8K P = 40960 B -> exactly 4 blocks/CU
//    (launch_bounds(256,4)); grid 1024 = 4/CU * 256 CU -> zero tail.
//  * P buffer: stride 64 + XOR swizzle (col ^ (l15&7)<<3) replaces pad-72.
//  * T5: s_setprio(1) around MFMA clusters.  T13: defer-max rescale skip.
//  * XCD swizzle kept: 1024 = 8 XCD * 128; 2 heads/XCD -> hot set ~3MB < L2.
// ---------------------------------------------------------------------------
__global__ __launch_bounds__(256, 4) void attn_part(
    const _Float16* __restrict__ KT, const _Float16* __restrict__ VT,
    const float* __restrict__ Qbuf,
    _Float16* __restrict__ p0, _Float16* __restrict__ p1,
    float* __restrict__ stats)
{
    __shared__ __align__(16) _Float16 Kb[2][8 * 64 * 8];   // 2 x 8 KB [ec][tl][ej]
    __shared__ __align__(16) _Float16 Vb[2][8 * 64 * 8];   // 2 x 8 KB [tc][e][tj]
    __shared__ __align__(16) _Float16 Pl[4][16 * 64];      // 8 KB per-wave P (swizzled)

    const int tid  = threadIdx.x;
    const int lane = tid & 63;
    const int wave = tid >> 6;
    const int l15  = lane & 15;
    const int quad = lane >> 4;

    // XCD-aware decomposition: 1024 = 8 XCD * (2 heads * 64 blocks)
    const int bx     = blockIdx.x;
    const int xcd    = bx & 7;
    const int j      = bx >> 3;             // 0..127 within this XCD
    const int hh     = j >> 6;              // which of the 2 heads here
    const int within = j & 63;              // qt*NSPLIT + sp
    const int bh     = xcd * 2 + hh;
    const int qt     = within >> 1;
    const int sp     = within & 1;

    const long base = (long)bh * S_LEN * EMB;
    const int qrow0 = qt * BM + wave * 16;
    const _Float16* kg = KT + (long)bh * 8 * S_LEN * 8;   // head base in KT8
    const _Float16* vgh = VT + (long)bh * 256 * 512;      // head base in VT8

    const int kb = sp * (NKT / NSPLIT), ke = kb + (NKT / NSPLIT);  // 16 tiles

    // ---- prologue: stage tile kb into buffer 0; load Q frags meanwhile ----
    {
        const int t0 = kb * BN;
        #pragma unroll
        for (int rr = 0; rr < 2; ++rr) {
            const int u = rr * 256 + tid;
            const int ec = u >> 6, tl = u & 63;
            gload_lds16(kg + ((long)ec * S_LEN + t0 + tl) * 8, &Kb[0][u * 8]);
        }
        const _Float16* vg = vgh + (long)(t0 >> 3) * 512;
        #pragma unroll
        for (int rr = 0; rr < 2; ++rr) {
            const int u = rr * 256 + tid;
            gload_lds16(vg + u * 8, &Vb[0][u * 8]);
        }
    }

    half8 qf[2];   // B-frag: Q[n = q-row l15][e = ks*32+quad*8+j]
    #pragma unroll
    for (int ks = 0; ks < 2; ++ks)
        qf[ks] = cvt8(Qbuf + base + (long)(qrow0 + l15) * EMB + ks * 32 + quad * 8);

    float4_t o[4];
    #pragma unroll
    for (int et = 0; et < 4; ++et) o[et] = (float4_t){0.f, 0.f, 0.f, 0.f};
    float m_run = M_INIT, l_run = 0.f;    // this lane's q-row = l15

    const int pswz = (l15 & 7) << 3;      // P column XOR-swizzle (16B granules)
    _Float16* Pw = Pl[wave];

    __syncthreads();                      // drains prologue vmcnt -> tile kb ready

    for (int kt = kb; kt < ke; ++kt) {
        const int cur = (kt - kb) & 1;
        const bool more = (kt + 1 < ke);

        // ---- issue next tile's staging into the other buffer (overlapped) ----
        if (more) {
            const int t0 = (kt + 1) * BN;
            #pragma unroll
            for (int rr = 0; rr < 2; ++rr) {
                const int u = rr * 256 + tid;
                const int ec = u >> 6, tl = u & 63;
                gload_lds16(kg + ((long)ec * S_LEN + t0 + tl) * 8,
                            &Kb[cur ^ 1][u * 8]);
            }
            const _Float16* vg = vgh + (long)(t0 >> 3) * 512;
            #pragma unroll
            for (int rr = 0; rr < 2; ++rr) {
                const int u = rr * 256 + tid;
                gload_lds16(vg + u * 8, &Vb[cur ^ 1][u * 8]);
            }
        }

        const _Float16* Kc = Kb[cur];
        const _Float16* Vc = Vb[cur];

        // ---- S^T = K Q^T : 4 n-tiles of 16 t-rows ----
        float4_t sacc[4];
        #pragma unroll
        for (int nt = 0; nt < 4; ++nt) sacc[nt] = (float4_t){0.f, 0.f, 0.f, 0.f};
        __builtin_amdgcn_s_setprio(1);
        #pragma unroll
        for (int nt = 0; nt < 4; ++nt)
            #pragma unroll
            for (int ks = 0; ks < 2; ++ks) {
                half8 kf = *reinterpret_cast<const half8*>(   // A: K[m=t][e]
                    Kc + (ks * 4 + quad) * 512 + (nt * 16 + l15) * 8);
                sacc[nt] = __builtin_amdgcn_mfma_f32_16x16x32_f16(
                    kf, qf[ks], sacc[nt], 0, 0, 0);
            }
        __builtin_amdgcn_s_setprio(0);

        // ---- softmax for q-row l15: 16 local values (t = nt*16+quad*4+r) ----
        float mx = sacc[0][0];
        #pragma unroll
        for (int nt = 0; nt < 4; ++nt)
            #pragma unroll
            for (int r = 0; r < 4; ++r) mx = fmaxf(mx, sacc[nt][r]);
        mx = fmaxf(mx, __shfl_xor(mx, 16));
        mx = fmaxf(mx, __shfl_xor(mx, 32));

        // T13 defer-max: keep stale m while growth <= THR (wave-uniform).
        if (!__all(mx - m_run <= DEFER_THR)) {
            const float mn = fmaxf(m_run, mx);
            const float alpha = __expf(fmaxf(m_run - mn, EXP_CLAMP));
            m_run = mn;
            l_run *= alpha;
            #pragma unroll
            for (int r = 0; r < 4; ++r) {              // rows quad*4+r
                const float ar = __shfl(alpha, quad * 4 + r);
                #pragma unroll
                for (int et = 0; et < 4; ++et) o[et][r] *= ar;
            }
        }

        float rsum = 0.f;
        #pragma unroll
        for (int nt = 0; nt < 4; ++nt) {
            half4 ph;
            #pragma unroll
            for (int r = 0; r < 4; ++r) {
                const float p = __expf(sacc[nt][r] - m_run);
                rsum += p;
                ph[r] = (_Float16)p;
            }
            // P[q=l15][t = nt*16 + quad*4 + 0..3] : one b64 write (swizzled)
            *reinterpret_cast<half4*>(
                &Pw[l15 * 64 + ((nt * 16 + quad * 4) ^ pswz)]) = ph;
        }
        rsum += __shfl_xor(rsum, 16);
        rsum += __shfl_xor(rsum, 32);
        l_run += rsum;
        // no barrier: P write->read is intra-wave (compiler lgkmcnt)

        // ---- O += P V : A-frag = P[m=l15][t=ts*32+quad*8+j], B from Vc ----
        __builtin_amdgcn_s_setprio(1);
        #pragma unroll
        for (int ts = 0; ts < 2; ++ts) {
            half8 pf = *reinterpret_cast<const half8*>(
                &Pw[l15 * 64 + ((ts * 32 + quad * 8) ^ pswz)]);
            #pragma unroll
            for (int et = 0; et < 4; ++et) {
                half8 vf = *reinterpret_cast<const half8*>(
                    Vc + (ts * 4 + quad) * 512 + (et * 16 + l15) * 8);
                o[et] = __builtin_amdgcn_mfma_f32_16x16x32_f16(pf, vf, o[et], 0, 0, 0);
            }
        }
        __builtin_amdgcn_s_setprio(0);

        // one barrier per tile: compiler drains vmcnt here, i.e. the prefetch
        // issued at loop top has had the whole compute phase to complete.
        if (more) __syncthreads();
    }

    // epilogue: normalized partial O-hat (f16) + (m,l) stats.
    _Float16* pp = (sp == 0) ? p0 : p1;
    #pragma unroll
    for (int r = 0; r < 4; ++r) {
        const float lr = __shfl(l_run, quad * 4 + r);    // row quad*4+r's sum
        const float inv = 1.f / lr;
        const int row = qrow0 + quad * 4 + r;            // 0..2047 within head
        const int R = bh * S_LEN + row;                  // 0..32767 global row
        #pragma unroll
        for (int et = 0; et < 4; ++et)
            pp[(long)R * EMB + et * 16 + l15] = (_Float16)(o[et][r] * inv);
    }
    if (lane < 16) {                                     // lane i owns q-row i
        const int R = bh * S_LEN + qrow0 + lane;
        stats[sp * 32768 + R] = m_run;
        stats[(NSPLIT + sp) * 32768 + R] = l_run;
    }
}

// ---------------------------------------------------------------------------
// Launch 4: combine the 2 partials. O = sum w_i*Ohat_i, f16-round, f32 store.
// Stale-m partials are exact here: w_i = l_i * exp(m_i - M) is invariant.
// ---------------------------------------------------------------------------
__global__ __launch_bounds__(256) void attn_combine(
    const _Float16* __restrict__ p0, const _Float16* __restrict__ p1,
    const float* __restrict__ stats, float* __restrict__ out)
{
    const int gid = blockIdx.x * 256 + threadIdx.x;      // 131072 threads
    const int R  = gid >> 2;
    const int c0 = (gid & 3) * 16;
    const float m0 = stats[R], m1 = stats[32768 + R];
    const float l0 = stats[2 * 32768 + R], l1 = stats[3 * 32768 + R];
    const float M = fmaxf(m0, m1);
    float w0 = l0 * __expf(fmaxf(m0 - M, EXP_CLAMP));
    float w1 = l1 * __expf(fmaxf(m1 - M, EXP_CLAMP));
    const float rinv = 1.f / (w0 + w1);
    w0 *= rinv; w1 *= rinv;
    const long i0 = (long)R * EMB + c0;
    #pragma unroll
    for (int h = 0; h < 2; ++h) {
        half8 a = *reinterpret_cast<const half8*>(p0 + i0 + h * 8);
        half8 b = *reinterpret_cast<const half8*>(p1 + i0 + h * 8);
        #pragma unroll
        for (int j = 0; j < 8; ++j)
            out[i0 + h * 8 + j] = (float)(_Float16)(
                w0 * (float)a[j] + w1 * (float)b[j]);
    }
}

// ---------------------------------------------------------------------------
// 4 launches. Buffer plan (no d_ws; stream-ordered liveness):
//   L1 proj_q:  d_in[0](f32) -> d_out (f32, f16-rounded, pre-scaled)
//   L2 proj_kv: d_in[1] -> KT8 = d_in[0][0,4MB); d_in[2] -> VT8 = d_in[0][4,8MB)
//   L3 attn_part: reads KT8/VT8/d_out; p0,p1 -> d_in[2][0,8MB) (v_in dead),
//               stats -> d_in[1][0,512KB) (k_in dead)
//   L4 combine -> d_out (Q dead)
// ---------------------------------------------------------------------------
extern "C" void kernel_launch(void* const* d_in, const int* in_sizes, int n_in,
                              void* d_out, int out_size, void* d_ws, size_t ws_size,
                              hipStream_t stream) {
    const float* q_in = (const float*)d_in[0];
    const float* k_in = (const float*)d_in[1];
    const float* v_in = (const float*)d_in[2];
    const float* Wq   = (const float*)d_in[3];
    const float* bq   = (const float*)d_in[4];
    const float* Wk   = (const float*)d_in[5];
    const float* bk   = (const float*)d_in[6];
    const float* Wv   = (const float*)d_in[7];
    const float* bv   = (const float*)d_in[8];
    float* out = (float*)d_out;

    _Float16* KT8   = (_Float16*)d_in[0];
    _Float16* VT8   = (_Float16*)((char*)d_in[0] + (4u << 20));
    _Float16* part0 = (_Float16*)d_in[2];
    _Float16* part1 = part0 + (long)2 * 1024 * 1024;           // +4 MB
    float*    stats = (float*)d_in[1];

    proj_q<<<256, 256, 0, stream>>>(q_in, Wq, bq, out);
    proj_kv<<<512, 256, 0, stream>>>(k_in, v_in, Wk, bk, Wv, bv, KT8, VT8);
    attn_part<<<16 * 32 * NSPLIT, 256, 0, stream>>>(KT8, VT8, out,
                                                    part0, part1, stats);
    attn_combine<<<512, 256, 0, stream>>>(part0, part1, stats, out);
}

// Round 3
// 139.885 us; speedup vs baseline: 1.0298x; 1.0188x over previous
//
#include <hip/hip_runtime.h>

// Problem constants (B=2, S=2048, H=8, E=64).
// Harness passes f16 tensors upcast to FLOAT32 (in and out). Internally f16
// compute (lossless re-narrowing of f16-origin data), fp32 MFMA accumulation.
#define S_LEN 2048
#define NH    8
#define EMB   64
#define BM    64    // q rows per block (16 per wave)
#define BN    64    // kv tile length
#define NKT   (S_LEN / BN)          // 32 kv tiles
#define NSPLIT 2    // KV splits: 16 bh x 32 qt x 2 = 1024 blocks = 4/CU exactly
#define M_INIT  (-1.0e4f)
#define EXP_CLAMP (-80.0f)
#define DEFER_THR 8.0f   // T13: skip rescale while max growth <= 8 (P <= e^8, f16-safe)

typedef _Float16 half8   __attribute__((ext_vector_type(8)));
typedef _Float16 half4   __attribute__((ext_vector_type(4)));
typedef float    float4_t __attribute__((ext_vector_type(4)));
typedef float    float8_t __attribute__((ext_vector_type(8)));

__device__ inline half8 cvt8(const float* p) {
    float8_t f = *reinterpret_cast<const float8_t*>(p);
    half8 h;
    #pragma unroll
    for (int j = 0; j < 8; ++j) h[j] = (_Float16)f[j];
    return h;
}

// async global->LDS, 16B per lane; LDS dest = uniform base + lane*16
__device__ inline void gload_lds16(const _Float16* g, _Float16* l) {
    __builtin_amdgcn_global_load_lds(
        (const __attribute__((address_space(1))) void*)g,
        (__attribute__((address_space(3))) void*)l, 16, 0, 0);
}

// ---------------------------------------------------------------------------
// Launch 1: Q projection -> d_out f32 [B,H,S,E], pre-scaled by 0.125.
// ---------------------------------------------------------------------------
__global__ __launch_bounds__(256) void proj_q(
    const float* __restrict__ X, const float* __restrict__ W,
    const float* __restrict__ bias, float* __restrict__ Out)
{
    const int tid  = threadIdx.x;
    const int lane = tid & 63;
    const int wave = tid >> 6;
    const int l15  = lane & 15;
    const int quad = lane >> 4;
    const int gwave = blockIdx.x * 4 + wave;

    half8 wf[4][2];
    #pragma unroll
    for (int ft = 0; ft < 4; ++ft)
        #pragma unroll
        for (int ks = 0; ks < 2; ++ks)
            wf[ft][ks] = cvt8(W + (ft * 16 + l15) * 64 + ks * 32 + quad * 8);
    float bv[4];
    #pragma unroll
    for (int ft = 0; ft < 4; ++ft) bv[ft] = bias[ft * 16 + l15];

    #pragma unroll
    for (int rt2 = 0; rt2 < 2; ++rt2) {
        const int rt = gwave * 2 + rt2;
        const int arow = rt * 16 + l15;
        half8 xf[2];
        #pragma unroll
        for (int ks = 0; ks < 2; ++ks)
            xf[ks] = cvt8(X + (long)arow * 64 + ks * 32 + quad * 8);
        float4_t acc[4];
        #pragma unroll
        for (int ft = 0; ft < 4; ++ft) {
            acc[ft] = (float4_t){0.f, 0.f, 0.f, 0.f};
            #pragma unroll
            for (int ks = 0; ks < 2; ++ks)
                acc[ft] = __builtin_amdgcn_mfma_f32_16x16x32_f16(
                    xf[ks], wf[ft][ks], acc[ft], 0, 0, 0);
        }
        #pragma unroll
        for (int r = 0; r < 4; ++r) {
            const int row = rt * 16 + quad * 4 + r;     // (b*S+s)*H+h
            const int b = row >> 14;
            const int s = (row >> 3) & 2047;
            const int h = row & 7;
            const long orow = ((long)(b * NH + h) * S_LEN + s) * EMB;
            #pragma unroll
            for (int ft = 0; ft < 4; ++ft) {
                const _Float16 v =
                    (_Float16)(acc[ft][r] + bv[ft]) * (_Float16)0.125f;
                Out[orow + ft * 16 + l15] = (float)v;
            }
        }
    }
}

// ---------------------------------------------------------------------------
// Launch 2: K and V projections fused, writing attention-ready layouts:
//   seg 0: K -> KT8[bh][f/8][s][f%8]
//   seg 1: V -> VT8[bh][s/8][f][s%8]
// ---------------------------------------------------------------------------
__global__ __launch_bounds__(256) void proj_kv(
    const float* __restrict__ k_in, const float* __restrict__ v_in,
    const float* __restrict__ Wk, const float* __restrict__ bk,
    const float* __restrict__ Wv, const float* __restrict__ bv_,
    _Float16* __restrict__ KT8, _Float16* __restrict__ VT8)
{
    const int seg = blockIdx.x >> 8;          // 0=K, 1=V
    const int bid = blockIdx.x & 255;
    const float* X    = seg ? v_in : k_in;
    const float* W    = seg ? Wv : Wk;
    const float* bias = seg ? bv_ : bk;

    const int tid  = threadIdx.x;
    const int lane = tid & 63;
    const int wave = tid >> 6;
    const int l15  = lane & 15;
    const int quad = lane >> 4;
    const int gwave = bid * 4 + wave;

    half8 wf[4][2];
    #pragma unroll
    for (int ft = 0; ft < 4; ++ft)
        #pragma unroll
        for (int ks = 0; ks < 2; ++ks)
            wf[ft][ks] = cvt8(W + (ft * 16 + l15) * 64 + ks * 32 + quad * 8);
    float bv[4];
    #pragma unroll
    for (int ft = 0; ft < 4; ++ft) bv[ft] = bias[ft * 16 + l15];

    #pragma unroll
    for (int rt2 = 0; rt2 < 2; ++rt2) {
        const int rt = gwave * 2 + rt2;
        const int arow = rt * 16 + l15;
        half8 xf[2];
        #pragma unroll
        for (int ks = 0; ks < 2; ++ks)
            xf[ks] = cvt8(X + (long)arow * 64 + ks * 32 + quad * 8);
        float4_t acc[4];
        #pragma unroll
        for (int ft = 0; ft < 4; ++ft) {
            acc[ft] = (float4_t){0.f, 0.f, 0.f, 0.f};
            #pragma unroll
            for (int ks = 0; ks < 2; ++ks)
                acc[ft] = __builtin_amdgcn_mfma_f32_16x16x32_f16(
                    xf[ks], wf[ft][ks], acc[ft], 0, 0, 0);
        }
        #pragma unroll
        for (int r = 0; r < 4; ++r) {
            const int row = rt * 16 + quad * 4 + r;     // (b*S+s)*H+h
            const int b = row >> 14;
            const int s = (row >> 3) & 2047;
            const int h = row & 7;
            const int bh = b * NH + h;
            #pragma unroll
            for (int ft = 0; ft < 4; ++ft) {
                const _Float16 v = (_Float16)(acc[ft][r] + bv[ft]);
                const int f = ft * 16 + l15;
                if (seg == 0)
                    KT8[(((long)bh * 8 + (f >> 3)) * S_LEN + s) * 8 + (f & 7)] = v;
                else
                    VT8[(((long)bh * 256 + (s >> 3)) * 64 + f) * 8 + (s & 7)] = v;
            }
        }
    }
}

// ---------------------------------------------------------------------------
// Launch 3: flash attention partials. KV-split=2, S^T orientation, BN=64.
// R3 changes (counters: latency-bound, 4 cross-lane DS ops on the per-tile
// serial chain, PV gated behind full softmax):
//  * T13 defer extended: common path has ZERO cross-lane ops. Local 16-max +
//    __all vote; full 2-shuffle row max + rescale only on trigger.
//  * l accumulated per-lane (l_part); single cross-lane reduce in epilogue.
//    Exact through combine: w = l*exp(m-M) invariant to stale m.
//  * PV interleaved with exp by nt-pairs: PV(ts) only needs P from
//    nt={2ts,2ts+1}, so its 4 MFMAs issue while the other pair's exps run.
//  * Double-buffered K/V staging, one barrier per tile, setprio, XCD swizzle,
//    4 blocks/CU exact grid -- unchanged from R2.
// ---------------------------------------------------------------------------
__global__ __launch_bounds__(256, 4) void attn_part(
    const _Float16* __restrict__ KT, const _Float16* __restrict__ VT,
    const float* __restrict__ Qbuf,
    _Float16* __restrict__ p0, _Float16* __restrict__ p1,
    float* __restrict__ stats)
{
    __shared__ __align__(16) _Float16 Kb[2][8 * 64 * 8];   // 2 x 8 KB [ec][tl][ej]
    __shared__ __align__(16) _Float16 Vb[2][8 * 64 * 8];   // 2 x 8 KB [tc][e][tj]
    __shared__ __align__(16) _Float16 Pl[4][16 * 64];      // 8 KB per-wave P (swizzled)

    const int tid  = threadIdx.x;
    const int lane = tid & 63;
    const int wave = tid >> 6;
    const int l15  = lane & 15;
    const int quad = lane >> 4;

    // XCD-aware decomposition: 1024 = 8 XCD * (2 heads * 64 blocks)
    const int bx     = blockIdx.x;
    const int xcd    = bx & 7;
    const int j      = bx >> 3;             // 0..127 within this XCD
    const int hh     = j >> 6;              // which of the 2 heads here
    const int within = j & 63;              // qt*NSPLIT + sp
    const int bh     = xcd * 2 + hh;
    const int qt     = within >> 1;
    const int sp     = within & 1;

    const long base = (long)bh * S_LEN * EMB;
    const int qrow0 = qt * BM + wave * 16;
    const _Float16* kg = KT + (long)bh * 8 * S_LEN * 8;   // head base in KT8
    const _Float16* vgh = VT + (long)bh * 256 * 512;      // head base in VT8

    const int kb = sp * (NKT / NSPLIT), ke = kb + (NKT / NSPLIT);  // 16 tiles

    // ---- prologue: stage tile kb into buffer 0; load Q frags meanwhile ----
    {
        const int t0 = kb * BN;
        #pragma unroll
        for (int rr = 0; rr < 2; ++rr) {
            const int u = rr * 256 + tid;
            const int ec = u >> 6, tl = u & 63;
            gload_lds16(kg + ((long)ec * S_LEN + t0 + tl) * 8, &Kb[0][u * 8]);
        }
        const _Float16* vg = vgh + (long)(t0 >> 3) * 512;
        #pragma unroll
        for (int rr = 0; rr < 2; ++rr) {
            const int u = rr * 256 + tid;
            gload_lds16(vg + u * 8, &Vb[0][u * 8]);
        }
    }

    half8 qf[2];   // B-frag: Q[n = q-row l15][e = ks*32+quad*8+j]
    #pragma unroll
    for (int ks = 0; ks < 2; ++ks)
        qf[ks] = cvt8(Qbuf + base + (long)(qrow0 + l15) * EMB + ks * 32 + quad * 8);

    float4_t o[4];
    #pragma unroll
    for (int et = 0; et < 4; ++et) o[et] = (float4_t){0.f, 0.f, 0.f, 0.f};
    float m_run  = M_INIT;     // running (possibly stale) max for q-row l15
    float l_part = 0.f;        // THIS LANE's partial sum for q-row l15

    const int pswz = (l15 & 7) << 3;      // P column XOR-swizzle (16B granules)
    _Float16* Pw = Pl[wave];

    __syncthreads();                      // drains prologue vmcnt -> tile kb ready

    for (int kt = kb; kt < ke; ++kt) {
        const int cur = (kt - kb) & 1;
        const bool more = (kt + 1 < ke);

        // ---- issue next tile's staging into the other buffer (overlapped) ----
        if (more) {
            const int t0 = (kt + 1) * BN;
            #pragma unroll
            for (int rr = 0; rr < 2; ++rr) {
                const int u = rr * 256 + tid;
                const int ec = u >> 6, tl = u & 63;
                gload_lds16(kg + ((long)ec * S_LEN + t0 + tl) * 8,
                            &Kb[cur ^ 1][u * 8]);
            }
            const _Float16* vg = vgh + (long)(t0 >> 3) * 512;
            #pragma unroll
            for (int rr = 0; rr < 2; ++rr) {
                const int u = rr * 256 + tid;
                gload_lds16(vg + u * 8, &Vb[cur ^ 1][u * 8]);
            }
        }

        const _Float16* Kc = Kb[cur];
        const _Float16* Vc = Vb[cur];

        // ---- S^T = K Q^T : 4 n-tiles of 16 t-rows ----
        float4_t sacc[4];
        #pragma unroll
        for (int nt = 0; nt < 4; ++nt) sacc[nt] = (float4_t){0.f, 0.f, 0.f, 0.f};
        __builtin_amdgcn_s_setprio(1);
        #pragma unroll
        for (int nt = 0; nt < 4; ++nt)
            #pragma unroll
            for (int ks = 0; ks < 2; ++ks) {
                half8 kf = *reinterpret_cast<const half8*>(   // A: K[m=t][e]
                    Kc + (ks * 4 + quad) * 512 + (nt * 16 + l15) * 8);
                sacc[nt] = __builtin_amdgcn_mfma_f32_16x16x32_f16(
                    kf, qf[ks], sacc[nt], 0, 0, 0);
            }
        __builtin_amdgcn_s_setprio(0);

        // ---- local max of this lane's 16 values (tree; no cross-lane) ----
        float mx = fmaxf(fmaxf(fmaxf(sacc[0][0], sacc[0][1]),
                               fmaxf(sacc[0][2], sacc[0][3])),
                         fmaxf(fmaxf(sacc[1][0], sacc[1][1]),
                               fmaxf(sacc[1][2], sacc[1][3])));
        mx = fmaxf(mx, fmaxf(fmaxf(fmaxf(sacc[2][0], sacc[2][1]),
                                   fmaxf(sacc[2][2], sacc[2][3])),
                             fmaxf(fmaxf(sacc[3][0], sacc[3][1]),
                                   fmaxf(sacc[3][2], sacc[3][3]))));

        // T13 defer: the wave-wide vote covers every row's every value, so
        // m_run stays a valid (stale) bound when no lane exceeds THR.
        if (!__all(mx - m_run <= DEFER_THR)) {
            // full row max (only on trigger): 2 shuffles
            float mr = fmaxf(mx, __shfl_xor(mx, 16));
            mr = fmaxf(mr, __shfl_xor(mr, 32));
            const float mn = fmaxf(m_run, mr);
            const float alpha = __expf(fmaxf(m_run - mn, EXP_CLAMP));
            m_run = mn;
            l_part *= alpha;              // own row's alpha: no shuffle
            #pragma unroll
            for (int r = 0; r < 4; ++r) { // o rows are quad*4+r
                const float ar = __shfl(alpha, quad * 4 + r);
                #pragma unroll
                for (int et = 0; et < 4; ++et) o[et][r] *= ar;
            }
        }

        // ---- exp + P store by nt-pairs, PV(ts) interleaved right after its
        //      pair is in LDS: MFMA issues while the next pair's exps run ----
        #pragma unroll
        for (int ts = 0; ts < 2; ++ts) {
            #pragma unroll
            for (int ntl = 0; ntl < 2; ++ntl) {
                const int nt = ts * 2 + ntl;
                half4 ph;
                #pragma unroll
                for (int r = 0; r < 4; ++r) {
                    const float p = __expf(sacc[nt][r] - m_run);
                    l_part += p;
                    ph[r] = (_Float16)p;
                }
                // P[q=l15][t = nt*16 + quad*4 + 0..3] : one b64 write (swizzled)
                *reinterpret_cast<half4*>(
                    &Pw[l15 * 64 + ((nt * 16 + quad * 4) ^ pswz)]) = ph;
            }
            // A-frag = P[m=l15][t = ts*32 + quad*8 + j] (intra-wave LDS RAW)
            half8 pf = *reinterpret_cast<const half8*>(
                &Pw[l15 * 64 + ((ts * 32 + quad * 8) ^ pswz)]);
            __builtin_amdgcn_s_setprio(1);
            #pragma unroll
            for (int et = 0; et < 4; ++et) {
                half8 vf = *reinterpret_cast<const half8*>(
                    Vc + (ts * 4 + quad) * 512 + (et * 16 + l15) * 8);
                o[et] = __builtin_amdgcn_mfma_f32_16x16x32_f16(pf, vf, o[et], 0, 0, 0);
            }
            __builtin_amdgcn_s_setprio(0);
        }

        // one barrier per tile: compiler drains vmcnt here, i.e. the prefetch
        // issued at loop top has had the whole compute phase to complete.
        if (more) __syncthreads();
    }

    // ---- epilogue: single cross-lane l reduction, then normalized O-hat ----
    float l_run = l_part;
    l_run += __shfl_xor(l_run, 16);
    l_run += __shfl_xor(l_run, 32);       // all lanes: full row sum for row l15

    _Float16* pp = (sp == 0) ? p0 : p1;
    #pragma unroll
    for (int r = 0; r < 4; ++r) {
        const float lr = __shfl(l_run, quad * 4 + r);    // row quad*4+r's sum
        const float inv = 1.f / lr;
        const int row = qrow0 + quad * 4 + r;            // 0..2047 within head
        const int R = bh * S_LEN + row;                  // 0..32767 global row
        #pragma unroll
        for (int et = 0; et < 4; ++et)
            pp[(long)R * EMB + et * 16 + l15] = (_Float16)(o[et][r] * inv);
    }
    if (lane < 16) {                                     // lane i owns q-row i
        const int R = bh * S_LEN + qrow0 + lane;
        stats[sp * 32768 + R] = m_run;
        stats[(NSPLIT + sp) * 32768 + R] = l_run;
    }
}

// ---------------------------------------------------------------------------
// Launch 4: combine the 2 partials. O = sum w_i*Ohat_i, f16-round, f32 store.
// Stale-m partials are exact here: w_i = l_i * exp(m_i - M) is invariant.
// ---------------------------------------------------------------------------
__global__ __launch_bounds__(256) void attn_combine(
    const _Float16* __restrict__ p0, const _Float16* __restrict__ p1,
    const float* __restrict__ stats, float* __restrict__ out)
{
    const int gid = blockIdx.x * 256 + threadIdx.x;      // 131072 threads
    const int R  = gid >> 2;
    const int c0 = (gid & 3) * 16;
    const float m0 = stats[R], m1 = stats[32768 + R];
    const float l0 = stats[2 * 32768 + R], l1 = stats[3 * 32768 + R];
    const float M = fmaxf(m0, m1);
    float w0 = l0 * __expf(fmaxf(m0 - M, EXP_CLAMP));
    float w1 = l1 * __expf(fmaxf(m1 - M, EXP_CLAMP));
    const float rinv = 1.f / (w0 + w1);
    w0 *= rinv; w1 *= rinv;
    const long i0 = (long)R * EMB + c0;
    #pragma unroll
    for (int h = 0; h < 2; ++h) {
        half8 a = *reinterpret_cast<const half8*>(p0 + i0 + h * 8);
        half8 b = *reinterpret_cast<const half8*>(p1 + i0 + h * 8);
        #pragma unroll
        for (int j = 0; j < 8; ++j)
            out[i0 + h * 8 + j] = (float)(_Float16)(
                w0 * (float)a[j] + w1 * (float)b[j]);
    }
}

// ---------------------------------------------------------------------------
// 4 launches. Buffer plan (no d_ws; stream-ordered liveness):
//   L1 proj_q:  d_in[0](f32) -> d_out (f32, f16-rounded, pre-scaled)
//   L2 proj_kv: d_in[1] -> KT8 = d_in[0][0,4MB); d_in[2] -> VT8 = d_in[0][4,8MB)
//   L3 attn_part: reads KT8/VT8/d_out; p0,p1 -> d_in[2][0,8MB) (v_in dead),
//               stats -> d_in[1][0,512KB) (k_in dead)
//   L4 combine -> d_out (Q dead)
// ---------------------------------------------------------------------------
extern "C" void kernel_launch(void* const* d_in, const int* in_sizes, int n_in,
                              void* d_out, int out_size, void* d_ws, size_t ws_size,
                              hipStream_t stream) {
    const float* q_in = (const float*)d_in[0];
    const float* k_in = (const float*)d_in[1];
    const float* v_in = (const float*)d_in[2];
    const float* Wq   = (const float*)d_in[3];
    const float* bq   = (const float*)d_in[4];
    const float* Wk   = (const float*)d_in[5];
    const float* bk   = (const float*)d_in[6];
    const float* Wv   = (const float*)d_in[7];
    const float* bv   = (const float*)d_in[8];
    float* out = (float*)d_out;

    _Float16* KT8   = (_Float16*)d_in[0];
    _Float16* VT8   = (_Float16*)((char*)d_in[0] + (4u << 20));
    _Float16* part0 = (_Float16*)d_in[2];
    _Float16* part1 = part0 + (long)2 * 1024 * 1024;           // +4 MB
    float*    stats = (float*)d_in[1];

    proj_q<<<256, 256, 0, stream>>>(q_in, Wq, bq, out);
    proj_kv<<<512, 256, 0, stream>>>(k_in, v_in, Wk, bk, Wv, bv, KT8, VT8);
    attn_part<<<16 * 32 * NSPLIT, 256, 0, stream>>>(KT8, VT8, out,
                                                    part0, part1, stats);
    attn_combine<<<512, 256, 0, stream>>>(part0, part1, stats, out);
}